// Round 1
// baseline (239.178 us; speedup 1.0000x reference)
//
#include <hip/hip_runtime.h>
#include <stdint.h>

#define BATCH 8
#define SEQ 2048
#define DIM 1024
#define MTOT (BATCH * SEQ)   // 16384

typedef __attribute__((ext_vector_type(8))) short short8;
typedef __attribute__((ext_vector_type(8))) unsigned short ushort8;
typedef __attribute__((ext_vector_type(4))) float floatx4;

// ---------- helpers ----------

__device__ __forceinline__ unsigned short f2bf(float f) {
  union { float f; unsigned u; } c; c.f = f;
  unsigned u = c.u;
  return (unsigned short)((u + 0x7FFFu + ((u >> 16) & 1u)) >> 16);
}
__device__ __forceinline__ float bf2f(unsigned short h) {
  union { unsigned u; float f; } c; c.u = ((unsigned)h) << 16;
  return c.f;
}

__device__ __forceinline__ void gll16(const void* g, void* l) {
  __builtin_amdgcn_global_load_lds(
      (__attribute__((address_space(1))) void*)(uintptr_t)g,
      (__attribute__((address_space(3))) void*)(uintptr_t)l,
      16, 0, 0);
}

// ---------- cast fp32->bf16 (B, W only; x is consumed fp32 by gemm1) ------

#define M4 (DIM * DIM / 4)    // 262144

__global__ __launch_bounds__(256) void cast2_kernel(
    const float* __restrict__ B, const float* __restrict__ W,
    unsigned short* __restrict__ Bb, unsigned short* __restrict__ Wb) {
  int i = blockIdx.x * 256 + threadIdx.x;
  const float4* s4;
  uint2* d2;
  int li;
  if (i < M4) {
    s4 = (const float4*)B; d2 = (uint2*)Bb; li = i;
  } else {
    s4 = (const float4*)W; d2 = (uint2*)Wb; li = i - M4;
  }
  float4 v = s4[li];
  uint2 o;
  o.x = (unsigned)f2bf(v.x) | ((unsigned)f2bf(v.y) << 16);
  o.y = (unsigned)f2bf(v.z) | ((unsigned)f2bf(v.w) << 16);
  d2[li] = o;
}

// ---------- GEMM1 fused: fp32 x staged+cast in regs, chunk scan, agg ------
// u[m][n] = sum_k x[m][k]*B[n][k]; per-column prefix scan over the 128-row
// m-tile, h_local written bf16, chunk aggregate published. No cross-block
// sync. A-operand is reg-staged (fp32 load -> bf16 cvt -> ds_write into the
// SAME linear layout gll16 produced; pre-swizzled global source unchanged).

__global__ __launch_bounds__(256) void gemm1_fused(
    const float* __restrict__ X,            // x fp32 [M x 1024]
    const unsigned short* __restrict__ B,   // Bb bf16 [1024 x 1024]
    unsigned short* __restrict__ u,         // h_local out bf16
    const float* __restrict__ Adiag,
    float* __restrict__ aggbuf) {           // [128][1024] fp32
  __shared__ unsigned short smem[16384];    // sA|sB, reused as sC (32 KB)
  __shared__ float segsum[2][128];
  unsigned short* sA = smem;
  unsigned short* sB = smem + 8192;

  const int tid = threadIdx.x;
  const int wave = tid >> 6, lane = tid & 63;

  // XCD-aware tile remap (all 8 nt-blocks of one mt land on one XCD)
  const int id = blockIdx.x;
  const int xcd = id & 7, j = id >> 3;
  const int mt = xcd * 16 + (j >> 3);
  const int nt = j & 7;
  const size_t m0 = (size_t)mt * 128;
  const int n0 = nt * 128;

  floatx4 acc[4][4] = {};

  const int srow = wave * 8 + (lane >> 3);
  const int scol = (((lane & 7) ^ ((lane >> 3) & 7)) * 8);  // XOR swizzle
  const float* gX = X + (m0 + srow) * 1024 + scol;
  const unsigned short* gB = B + ((size_t)n0 + srow) * 1024 + scol;
  unsigned short* lA = sA + wave * 8 * 64 + lane * 8;  // linear dest (lane*16B)
  unsigned short* lB = sB + wave * 8 * 64;

  const int fr = lane & 15;
  const int frs = fr & 7;
  const int kb = lane >> 4;
  const int wm = (wave & 1) * 64, wn = (wave >> 1) * 64;

  for (int kt = 0; kt < 1024; kt += 64) {
    // A: fp32 reg loads (issued first so their waits leave B-gll16 in flight)
    float4 av[4][2];
#pragma unroll
    for (int r = 0; r < 4; ++r) {
      const float* p = gX + (size_t)r * 32 * 1024 + kt;
      av[r][0] = *(const float4*)p;
      av[r][1] = *(const float4*)(p + 4);
    }
    // B: direct-to-LDS
#pragma unroll
    for (int r = 0; r < 4; ++r)
      gll16(gB + (size_t)r * 32 * 1024 + kt, lB + r * 32 * 64);
    // convert + ds_write A (compiler inserts vmcnt for av uses)
#pragma unroll
    for (int r = 0; r < 4; ++r) {
      ushort8 o;
      o[0] = f2bf(av[r][0].x); o[1] = f2bf(av[r][0].y);
      o[2] = f2bf(av[r][0].z); o[3] = f2bf(av[r][0].w);
      o[4] = f2bf(av[r][1].x); o[5] = f2bf(av[r][1].y);
      o[6] = f2bf(av[r][1].z); o[7] = f2bf(av[r][1].w);
      *(ushort8*)(lA + r * 32 * 64) = o;
    }
    asm volatile("s_waitcnt vmcnt(0)" ::: "memory");
    __syncthreads();
#pragma unroll
    for (int kk = 0; kk < 64; kk += 32) {
      short8 af[4], bfv[4];
#pragma unroll
      for (int i = 0; i < 4; ++i)
        af[i] = *(const short8*)(sA + (wm + i * 16 + fr) * 64 +
                                 ((((kk >> 3) + kb) ^ frs) * 8));
#pragma unroll
      for (int jj = 0; jj < 4; ++jj)
        bfv[jj] = *(const short8*)(sB + (wn + jj * 16 + fr) * 64 +
                                   ((((kk >> 3) + kb) ^ frs) * 8));
#pragma unroll
      for (int i = 0; i < 4; ++i)
#pragma unroll
        for (int jj = 0; jj < 4; ++jj)
          acc[i][jj] = __builtin_amdgcn_mfma_f32_16x16x32_bf16(
              af[i], bfv[jj], acc[i][jj], 0, 0, 0);
    }
    __syncthreads();
  }

  // stage u tile in LDS (C/D map: col=lane&15, row=(lane>>4)*4+reg)
  const int col = lane & 15;
  const int row4 = (lane >> 4) * 4;
  unsigned short* sC = smem;  // 128x128 bf16
#pragma unroll
  for (int i = 0; i < 4; ++i)
#pragma unroll
    for (int jj = 0; jj < 4; ++jj)
#pragma unroll
      for (int r = 0; r < 4; ++r)
        sC[(wm + i * 16 + row4 + r) * 128 + wn + jj * 16 + col] =
            f2bf(acc[i][jj][r]);
  __syncthreads();

  // chunk-local scan: 2 segments x 64 t per column (tid -> col, seg)
  const int colv = tid & 127;
  const int seg = tid >> 7;
  const float a = Adiag[n0 + colv];
  {
    float s = 0.f;
    const int t0 = seg * 64;
#pragma unroll 8
    for (int t = 0; t < 64; ++t) {
      int idx = (t0 + t) * 128 + colv;
      s = fmaf(a, s, bf2f(sC[idx]));
      sC[idx] = f2bf(s);
    }
    segsum[seg][colv] = s;
  }
  __syncthreads();

  // correct rows 64..127 with seg-0 end state; publish aggregate
  {
    float a2 = a * a, a4 = a2 * a2, a8 = a4 * a4, a16 = a8 * a8;
    float a32 = a16 * a16, a64 = a32 * a32;
    const float s0 = segsum[0][colv];
    const int t0 = 64 + seg * 32;
    float apow = seg ? a32 * a : a;  // a^(t0-64+1)
#pragma unroll 8
    for (int t = 0; t < 32; ++t) {
      int idx = (t0 + t) * 128 + colv;
      sC[idx] = f2bf(fmaf(apow, s0, bf2f(sC[idx])));
      apow *= a;
    }
    if (seg)
      aggbuf[(size_t)mt * 1024 + n0 + colv] =
          fmaf(a64, s0, segsum[1][colv]);
  }
  __syncthreads();

  // coalesced 16B h_local stores
#pragma unroll
  for (int s = 0; s < 8; ++s) {
    int row = wave * 32 + s * 4 + (lane >> 4);
    int c8 = (lane & 15) * 8;
    *(ushort8*)(u + (m0 + row) * (size_t)1024 + n0 + c8) =
        *(const ushort8*)(sC + row * 128 + c8);
  }
}

// ---------- combine: exclusive scan of 16 chunk aggregates per (b, n) ------

__global__ __launch_bounds__(256) void combine_kernel(
    const float* __restrict__ agg, float* __restrict__ carry,
    const float* __restrict__ Adiag) {
  const int id = blockIdx.x * 256 + threadIdx.x;  // 0..8191
  const int b = id >> 10, n = id & (DIM - 1);
  float a = Adiag[n];
  float aL = a;
#pragma unroll
  for (int i = 0; i < 7; ++i) aL *= aL;  // a^128
  float s = 0.f;
#pragma unroll
  for (int c = 0; c < 16; ++c) {
    size_t idx = (size_t)(b * 16 + c) * 1024 + n;
    float local = agg[idx];
    carry[idx] = s;           // carry-in for chunk c
    s = fmaf(aL, s, local);
  }
}

// ---------- GEMM2 fused: y = (h_local + a^(t+1)*carry) . W^T + bias -------
// apply_kernel folded into the A-staging: reg-load h_local bf16, fma the
// carry term (a^(t+1) via v_log/v_exp, same math as the old apply pass),
// cvt back to bf16, ds_write into the identical linear LDS layout.

__global__ __launch_bounds__(256) void gemm2_fused(
    const unsigned short* __restrict__ A,   // h_local bf16
    const unsigned short* __restrict__ Bw,  // Wb bf16
    float* __restrict__ C, const float* __restrict__ bias,
    const float* __restrict__ Adiag, const float* __restrict__ carry) {
  __shared__ unsigned short smem[16384];
  unsigned short* sA = smem;
  unsigned short* sB = smem + 8192;

  const int tid = threadIdx.x;
  const int wave = tid >> 6, lane = tid & 63;

  const int id = blockIdx.x;
  const int xcd = id & 7, j = id >> 3;
  const int mt = xcd * 16 + (j >> 3);
  const int nt = j & 7;
  const size_t m0 = (size_t)mt * 128;
  const int n0 = nt * 128;

  floatx4 acc[4][4] = {};

  const int srow = wave * 8 + (lane >> 3);           // local t in 0..31 (+r*32)
  const int scol = (((lane & 7) ^ ((lane >> 3) & 7)) * 8);
  const unsigned short* gA = A + (m0 + srow) * 1024 + scol;
  const unsigned short* gB = Bw + ((size_t)n0 + srow) * 1024 + scol;
  unsigned short* lA = sA + wave * 8 * 64 + lane * 8;
  unsigned short* lB = sB + wave * 8 * 64;
  const float* cbase = carry + (size_t)mt * 1024;

  const int fr = lane & 15;
  const int frs = fr & 7;
  const int kb = lane >> 4;
  const int wm = (wave & 1) * 64, wn = (wave >> 1) * 64;

  for (int kt = 0; kt < 1024; kt += 64) {
    // A: h_local bf16 reg loads + per-column a / carry (L2-hot, 4 KB rows)
    ushort8 hv[4];
#pragma unroll
    for (int r = 0; r < 4; ++r)
      hv[r] = *(const ushort8*)(gA + (size_t)r * 32 * 1024 + kt);
    float4 la0 = *(const float4*)(Adiag + kt + scol);
    float4 la1 = *(const float4*)(Adiag + kt + scol + 4);
    float4 cf0 = *(const float4*)(cbase + kt + scol);
    float4 cf1 = *(const float4*)(cbase + kt + scol + 4);
    // B: direct-to-LDS
#pragma unroll
    for (int r = 0; r < 4; ++r)
      gll16(gB + (size_t)r * 32 * 1024 + kt, lB + r * 32 * 64);

    // a^(t+1) for t = srow + r*32: exp2(log2(a)*(srow+1)), then *= a^32
    float la[8] = {la0.x, la0.y, la0.z, la0.w, la1.x, la1.y, la1.z, la1.w};
    float cf[8] = {cf0.x, cf0.y, cf0.z, cf0.w, cf1.x, cf1.y, cf1.z, cf1.w};
    float ap[8], a32[8];
#pragma unroll
    for (int q = 0; q < 8; ++q) {
      float lg = __builtin_amdgcn_logf(la[q]);            // v_log_f32 = log2
      ap[q] = __builtin_amdgcn_exp2f(lg * (float)(srow + 1));
      a32[q] = __builtin_amdgcn_exp2f(lg * 32.0f);
    }
#pragma unroll
    for (int r = 0; r < 4; ++r) {
      ushort8 o;
#pragma unroll
      for (int q = 0; q < 8; ++q) {
        o[q] = f2bf(fmaf(ap[q], cf[q], bf2f(hv[r][q])));
        ap[q] *= a32[q];
      }
      *(ushort8*)(lA + r * 32 * 64) = o;
    }
    asm volatile("s_waitcnt vmcnt(0)" ::: "memory");
    __syncthreads();
#pragma unroll
    for (int kk = 0; kk < 64; kk += 32) {
      short8 af[4], bfv[4];
#pragma unroll
      for (int i = 0; i < 4; ++i)
        af[i] = *(const short8*)(sA + (wm + i * 16 + fr) * 64 +
                                 ((((kk >> 3) + kb) ^ frs) * 8));
#pragma unroll
      for (int jj = 0; jj < 4; ++jj)
        bfv[jj] = *(const short8*)(sB + (wn + jj * 16 + fr) * 64 +
                                   ((((kk >> 3) + kb) ^ frs) * 8));
#pragma unroll
      for (int i = 0; i < 4; ++i)
#pragma unroll
        for (int jj = 0; jj < 4; ++jj)
          acc[i][jj] = __builtin_amdgcn_mfma_f32_16x16x32_bf16(
              af[i], bfv[jj], acc[i][jj], 0, 0, 0);
    }
    __syncthreads();
  }

  const int col = lane & 15;
  const int row4 = (lane >> 4) * 4;
#pragma unroll
  for (int i = 0; i < 4; ++i)
#pragma unroll
    for (int jj = 0; jj < 4; ++jj)
#pragma unroll
      for (int r = 0; r < 4; ++r) {
        size_t m = m0 + wm + i * 16 + row4 + r;
        int n = n0 + wn + jj * 16 + col;
        C[m * 1024 + n] = acc[i][jj][r] + bias[n];
      }
}

// ---------- launcher ----------

extern "C" void kernel_launch(void* const* d_in, const int* in_sizes, int n_in,
                              void* d_out, int out_size, void* d_ws,
                              size_t ws_size, hipStream_t stream) {
  const float* x    = (const float*)d_in[0];
  const float* A    = (const float*)d_in[1];
  const float* B    = (const float*)d_in[2];
  const float* W    = (const float*)d_in[3];
  const float* bias = (const float*)d_in[4];

  char* ws = (char*)d_ws;
  unsigned short* ubuf = (unsigned short*)ws;              // 32 MB (h_local)
  unsigned short* Bb   = (unsigned short*)(ws + 33554432); //  2 MB
  unsigned short* Wb   = (unsigned short*)(ws + 35651584); //  2 MB
  float* aggbuf        = (float*)(ws + 37748736);          // 512 KB
  float* carry         = (float*)(ws + 38273024);          // 512 KB

  cast2_kernel<<<2 * M4 / 256, 256, 0, stream>>>(B, W, Bb, Wb);

  gemm1_fused<<<1024, 256, 0, stream>>>(x, Bb, ubuf, A, aggbuf);

  combine_kernel<<<32, 256, 0, stream>>>(aggbuf, carry, A);

  gemm2_fused<<<1024, 256, 0, stream>>>(ubuf, Wb, (float*)d_out, bias, A, carry);
}

// Round 2
// 238.620 us; speedup vs baseline: 1.0023x; 1.0023x over previous
//
#include <hip/hip_runtime.h>
#include <stdint.h>

#define BATCH 8
#define SEQ 2048
#define DIM 1024
#define MTOT (BATCH * SEQ)   // 16384

typedef __attribute__((ext_vector_type(8))) short short8;
typedef __attribute__((ext_vector_type(8))) unsigned short ushort8;
typedef __attribute__((ext_vector_type(4))) float floatx4;

// ---------- helpers ----------

__device__ __forceinline__ unsigned short f2bf(float f) {
  union { float f; unsigned u; } c; c.f = f;
  unsigned u = c.u;
  return (unsigned short)((u + 0x7FFFu + ((u >> 16) & 1u)) >> 16);
}
__device__ __forceinline__ float bf2f(unsigned short h) {
  union { unsigned u; float f; } c; c.u = ((unsigned)h) << 16;
  return c.f;
}

__device__ __forceinline__ void gll16(const void* g, void* l) {
  __builtin_amdgcn_global_load_lds(
      (__attribute__((address_space(1))) void*)(uintptr_t)g,
      (__attribute__((address_space(3))) void*)(uintptr_t)l,
      16, 0, 0);
}

// ---------- cast fp32->bf16 (x, B, W), one float4 -> uint2 per thread ------

#define X4 (MTOT * DIM / 4)   // 4194304
#define M4 (DIM * DIM / 4)    // 262144

__global__ __launch_bounds__(256) void cast3_kernel(
    const float* __restrict__ x, const float* __restrict__ B,
    const float* __restrict__ W, unsigned short* __restrict__ xb,
    unsigned short* __restrict__ Bb, unsigned short* __restrict__ Wb) {
  int i = blockIdx.x * 256 + threadIdx.x;
  const float4* s4;
  uint2* d2;
  int li;
  if (i < X4) {
    s4 = (const float4*)x; d2 = (uint2*)xb; li = i;
  } else if (i < X4 + M4) {
    s4 = (const float4*)B; d2 = (uint2*)Bb; li = i - X4;
  } else {
    s4 = (const float4*)W; d2 = (uint2*)Wb; li = i - X4 - M4;
  }
  float4 v = s4[li];
  uint2 o;
  o.x = (unsigned)f2bf(v.x) | ((unsigned)f2bf(v.y) << 16);
  o.y = (unsigned)f2bf(v.z) | ((unsigned)f2bf(v.w) << 16);
  d2[li] = o;
}

// ---------- GEMM1 fused with chunk-local scan + aggregate publish ----------
// Round-0 verified form: bf16 A and B both staged via global_load_lds.
// u[m][n] = sum_k x[m][k]*B[n][k]; then per-column prefix scan over the
// 128-row m-tile (one seq chunk), h_local written out bf16, chunk aggregate
// (state at t=127, zero carry-in) published to aggbuf. NO cross-block sync.

__global__ __launch_bounds__(256) void gemm1_fused(
    const unsigned short* __restrict__ A,   // xb bf16 [M x 1024]
    const unsigned short* __restrict__ B,   // Bb bf16 [1024 x 1024]
    unsigned short* __restrict__ u,         // h_local out bf16
    const float* __restrict__ Adiag,
    float* __restrict__ aggbuf) {           // [128][1024] fp32
  __shared__ unsigned short smem[16384];    // sA|sB, reused as sC (32 KB)
  __shared__ float segsum[2][128];
  unsigned short* sA = smem;
  unsigned short* sB = smem + 8192;

  const int tid = threadIdx.x;
  const int wave = tid >> 6, lane = tid & 63;

  // XCD-aware tile remap (measured FETCH=ideal)
  const int id = blockIdx.x;
  const int xcd = id & 7, j = id >> 3;
  const int mt = xcd * 16 + (j >> 3);
  const int nt = j & 7;
  const size_t m0 = (size_t)mt * 128;
  const int n0 = nt * 128;

  floatx4 acc[4][4] = {};

  const int srow = wave * 8 + (lane >> 3);
  const int scol = (((lane & 7) ^ ((lane >> 3) & 7)) * 8);  // XOR swizzle
  const unsigned short* gA = A + (m0 + srow) * 1024 + scol;
  const unsigned short* gB = B + ((size_t)n0 + srow) * 1024 + scol;
  unsigned short* lA = sA + wave * 8 * 64;
  unsigned short* lB = sB + wave * 8 * 64;

  const int fr = lane & 15;
  const int frs = fr & 7;
  const int kb = lane >> 4;
  const int wm = (wave & 1) * 64, wn = (wave >> 1) * 64;

  for (int kt = 0; kt < 1024; kt += 64) {
#pragma unroll
    for (int r = 0; r < 4; ++r) {
      gll16(gA + (size_t)r * 32 * 1024 + kt, lA + r * 32 * 64);
      gll16(gB + (size_t)r * 32 * 1024 + kt, lB + r * 32 * 64);
    }
    asm volatile("s_waitcnt vmcnt(0)" ::: "memory");
    __syncthreads();
#pragma unroll
    for (int kk = 0; kk < 64; kk += 32) {
      short8 af[4], bfv[4];
#pragma unroll
      for (int i = 0; i < 4; ++i)
        af[i] = *(const short8*)(sA + (wm + i * 16 + fr) * 64 +
                                 ((((kk >> 3) + kb) ^ frs) * 8));
#pragma unroll
      for (int jj = 0; jj < 4; ++jj)
        bfv[jj] = *(const short8*)(sB + (wn + jj * 16 + fr) * 64 +
                                   ((((kk >> 3) + kb) ^ frs) * 8));
#pragma unroll
      for (int i = 0; i < 4; ++i)
#pragma unroll
        for (int jj = 0; jj < 4; ++jj)
          acc[i][jj] = __builtin_amdgcn_mfma_f32_16x16x32_bf16(
              af[i], bfv[jj], acc[i][jj], 0, 0, 0);
    }
    __syncthreads();
  }

  // stage u tile in LDS (C/D map: col=lane&15, row=(lane>>4)*4+reg)
  const int col = lane & 15;
  const int row4 = (lane >> 4) * 4;
  unsigned short* sC = smem;  // 128x128 bf16
#pragma unroll
  for (int i = 0; i < 4; ++i)
#pragma unroll
    for (int jj = 0; jj < 4; ++jj)
#pragma unroll
      for (int r = 0; r < 4; ++r)
        sC[(wm + i * 16 + row4 + r) * 128 + wn + jj * 16 + col] =
            f2bf(acc[i][jj][r]);
  __syncthreads();

  // chunk-local scan: 2 segments x 64 t per column (tid -> col, seg)
  const int colv = tid & 127;
  const int seg = tid >> 7;
  const float a = Adiag[n0 + colv];
  {
    float s = 0.f;
    const int t0 = seg * 64;
#pragma unroll 8
    for (int t = 0; t < 64; ++t) {
      int idx = (t0 + t) * 128 + colv;
      s = fmaf(a, s, bf2f(sC[idx]));
      sC[idx] = f2bf(s);
    }
    segsum[seg][colv] = s;
  }
  __syncthreads();

  // correct rows 64..127 with seg-0 end state; publish aggregate
  {
    float a2 = a * a, a4 = a2 * a2, a8 = a4 * a4, a16 = a8 * a8;
    float a32 = a16 * a16, a64 = a32 * a32;
    const float s0 = segsum[0][colv];
    const int t0 = 64 + seg * 32;
    float apow = seg ? a32 * a : a;  // a^(t0-64+1)
#pragma unroll 8
    for (int t = 0; t < 32; ++t) {
      int idx = (t0 + t) * 128 + colv;
      sC[idx] = f2bf(fmaf(apow, s0, bf2f(sC[idx])));
      apow *= a;
    }
    if (seg)
      aggbuf[(size_t)mt * 1024 + n0 + colv] =
          fmaf(a64, s0, segsum[1][colv]);
  }
  __syncthreads();

  // coalesced 16B h_local stores
#pragma unroll
  for (int s = 0; s < 8; ++s) {
    int row = wave * 32 + s * 4 + (lane >> 4);
    int c8 = (lane & 15) * 8;
    *(ushort8*)(u + (m0 + row) * (size_t)1024 + n0 + c8) =
        *(const ushort8*)(sC + row * 128 + c8);
  }
}

// ---------- combine: exclusive scan of 16 chunk aggregates per (b, n) ------

__global__ __launch_bounds__(256) void combine_kernel(
    const float* __restrict__ agg, float* __restrict__ carry,
    const float* __restrict__ Adiag) {
  const int id = blockIdx.x * 256 + threadIdx.x;  // 0..8191
  const int b = id >> 10, n = id & (DIM - 1);
  float a = Adiag[n];
  float aL = a;
#pragma unroll
  for (int i = 0; i < 7; ++i) aL *= aL;  // a^128
  float s = 0.f;
#pragma unroll
  for (int c = 0; c < 16; ++c) {
    size_t idx = (size_t)(b * 16 + c) * 1024 + n;
    float local = agg[idx];
    carry[idx] = s;           // carry-in for chunk c
    s = fmaf(aL, s, local);
  }
}

// ---------- GEMM2 fused: y = (h_local + a^(t+1)*carry) . W^T + bias -------
// Round-1 verified form: apply_kernel folded into the A-staging: reg-load
// h_local bf16 (same 16B/lane as gll16), fma the carry term (a^(t+1) via
// v_log/v_exp, same math as the old apply pass), cvt back to bf16, ds_write
// into the identical linear LDS layout.

__global__ __launch_bounds__(256) void gemm2_fused(
    const unsigned short* __restrict__ A,   // h_local bf16
    const unsigned short* __restrict__ Bw,  // Wb bf16
    float* __restrict__ C, const float* __restrict__ bias,
    const float* __restrict__ Adiag, const float* __restrict__ carry) {
  __shared__ unsigned short smem[16384];
  unsigned short* sA = smem;
  unsigned short* sB = smem + 8192;

  const int tid = threadIdx.x;
  const int wave = tid >> 6, lane = tid & 63;

  const int id = blockIdx.x;
  const int xcd = id & 7, j = id >> 3;
  const int mt = xcd * 16 + (j >> 3);
  const int nt = j & 7;
  const size_t m0 = (size_t)mt * 128;
  const int n0 = nt * 128;

  floatx4 acc[4][4] = {};

  const int srow = wave * 8 + (lane >> 3);           // local t in 0..31 (+r*32)
  const int scol = (((lane & 7) ^ ((lane >> 3) & 7)) * 8);
  const unsigned short* gA = A + (m0 + srow) * 1024 + scol;
  const unsigned short* gB = Bw + ((size_t)n0 + srow) * 1024 + scol;
  unsigned short* lA = sA + wave * 8 * 64 + lane * 8;
  unsigned short* lB = sB + wave * 8 * 64;
  const float* cbase = carry + (size_t)mt * 1024;

  const int fr = lane & 15;
  const int frs = fr & 7;
  const int kb = lane >> 4;
  const int wm = (wave & 1) * 64, wn = (wave >> 1) * 64;

  for (int kt = 0; kt < 1024; kt += 64) {
    // A: h_local bf16 reg loads + per-column a / carry (L2-hot, 4 KB rows)
    ushort8 hv[4];
#pragma unroll
    for (int r = 0; r < 4; ++r)
      hv[r] = *(const ushort8*)(gA + (size_t)r * 32 * 1024 + kt);
    float4 la0 = *(const float4*)(Adiag + kt + scol);
    float4 la1 = *(const float4*)(Adiag + kt + scol + 4);
    float4 cf0 = *(const float4*)(cbase + kt + scol);
    float4 cf1 = *(const float4*)(cbase + kt + scol + 4);
    // B: direct-to-LDS
#pragma unroll
    for (int r = 0; r < 4; ++r)
      gll16(gB + (size_t)r * 32 * 1024 + kt, lB + r * 32 * 64);

    // a^(t+1) for t = srow + r*32: exp2(log2(a)*(srow+1)), then *= a^32
    float la[8] = {la0.x, la0.y, la0.z, la0.w, la1.x, la1.y, la1.z, la1.w};
    float cf[8] = {cf0.x, cf0.y, cf0.z, cf0.w, cf1.x, cf1.y, cf1.z, cf1.w};
    float ap[8], a32[8];
#pragma unroll
    for (int q = 0; q < 8; ++q) {
      float lg = __builtin_amdgcn_logf(la[q]);            // v_log_f32 = log2
      ap[q] = __builtin_amdgcn_exp2f(lg * (float)(srow + 1));
      a32[q] = __builtin_amdgcn_exp2f(lg * 32.0f);
    }
#pragma unroll
    for (int r = 0; r < 4; ++r) {
      ushort8 o;
#pragma unroll
      for (int q = 0; q < 8; ++q) {
        o[q] = f2bf(fmaf(ap[q], cf[q], bf2f(hv[r][q])));
        ap[q] *= a32[q];
      }
      *(ushort8*)(lA + r * 32 * 64) = o;
    }
    asm volatile("s_waitcnt vmcnt(0)" ::: "memory");
    __syncthreads();
#pragma unroll
    for (int kk = 0; kk < 64; kk += 32) {
      short8 af[4], bfv[4];
#pragma unroll
      for (int i = 0; i < 4; ++i)
        af[i] = *(const short8*)(sA + (wm + i * 16 + fr) * 64 +
                                 ((((kk >> 3) + kb) ^ frs) * 8));
#pragma unroll
      for (int jj = 0; jj < 4; ++jj)
        bfv[jj] = *(const short8*)(sB + (wn + jj * 16 + fr) * 64 +
                                   ((((kk >> 3) + kb) ^ frs) * 8));
#pragma unroll
      for (int i = 0; i < 4; ++i)
#pragma unroll
        for (int jj = 0; jj < 4; ++jj)
          acc[i][jj] = __builtin_amdgcn_mfma_f32_16x16x32_bf16(
              af[i], bfv[jj], acc[i][jj], 0, 0, 0);
    }
    __syncthreads();
  }

  const int col = lane & 15;
  const int row4 = (lane >> 4) * 4;
#pragma unroll
  for (int i = 0; i < 4; ++i)
#pragma unroll
    for (int jj = 0; jj < 4; ++jj)
#pragma unroll
      for (int r = 0; r < 4; ++r) {
        size_t m = m0 + wm + i * 16 + row4 + r;
        int n = n0 + wn + jj * 16 + col;
        C[m * 1024 + n] = acc[i][jj][r] + bias[n];
      }
}

// ---------- launcher ----------

extern "C" void kernel_launch(void* const* d_in, const int* in_sizes, int n_in,
                              void* d_out, int out_size, void* d_ws,
                              size_t ws_size, hipStream_t stream) {
  const float* x    = (const float*)d_in[0];
  const float* A    = (const float*)d_in[1];
  const float* B    = (const float*)d_in[2];
  const float* W    = (const float*)d_in[3];
  const float* bias = (const float*)d_in[4];

  char* ws = (char*)d_ws;
  unsigned short* xb   = (unsigned short*)ws;              // 32 MB
  unsigned short* ubuf = (unsigned short*)(ws + 33554432); // 32 MB (h_local)
  unsigned short* Bb   = (unsigned short*)(ws + 67108864); //  2 MB
  unsigned short* Wb   = (unsigned short*)(ws + 69206016); //  2 MB
  float* aggbuf        = (float*)(ws + 71303168);          // 512 KB
  float* carry         = (float*)(ws + 71827456);          // 512 KB

  cast3_kernel<<<(X4 + 2 * M4) / 256, 256, 0, stream>>>(x, B, W, xb, Bb, Wb);

  gemm1_fused<<<1024, 256, 0, stream>>>(xb, Bb, ubuf, A, aggbuf);

  combine_kernel<<<32, 256, 0, stream>>>(aggbuf, carry, A);

  gemm2_fused<<<1024, 256, 0, stream>>>(ubuf, Wb, (float*)d_out, bias, A, carry);
}